// Round 7
// baseline (304.218 us; speedup 1.0000x reference)
//
#include <hip/hip_runtime.h>
#include <hip/hip_fp16.h>
#include <math.h>

#define NT 100000
#define B_GRAPHS 50
#define NE 1600000
#define V 15000
#define D 128
#define NODES_PER_GRAPH (NT / B_GRAPHS)   // 2000

#define POOL_N (B_GRAPHS * D + B_GRAPHS)  // 6450

// ---- dst binning: 128 dsts/bin -> 782 private bins, 1 binsort block each ----
#define BSH2 7
#define BD2 128
#define NBIN2 ((NT + BD2 - 1) / BD2)            // 782
#define ST2 2432                                // stage records/bin (mean 2046 + 8.5 sigma)
#define SLK2 512                                // row padding slack (128 rows x3 -> 384)
#define PAY2 (ST2 + SLK2)                       // 2944, x4 aligned
#define BUF2 PAY2                               // 23.5 KB LDS sort buffer
#define PAY_TAIL 512
#define EPB 4096                                // edges per binfill block
#define NFB ((NE + EPB - 1) / EPB)              // 391
#define PR 16
#define PROJ_BLOCKS ((V + PR - 1) / PR)         // 938

// ---- layer-2 src-binned contraction (src bins stay 391 x 256) ----
#define NBIN 391
#define SS_STRIDE 4608
#define NPART NBIN                              // 391 pool partials

typedef _Float16 half2_t __attribute__((ext_vector_type(2)));

#if defined(__has_builtin)
#if __has_builtin(__builtin_amdgcn_fdot2)
#define HAVE_FDOT2 1
#endif
#endif

__device__ __forceinline__ float dot2acc(unsigned a, unsigned b, float c) {
#ifdef HAVE_FDOT2
  return __builtin_amdgcn_fdot2(__builtin_bit_cast(half2_t, a),
                                __builtin_bit_cast(half2_t, b), c, false);
#else
  float a0 = __half2float(__ushort_as_half((unsigned short)(a & 0xffffu)));
  float a1 = __half2float(__ushort_as_half((unsigned short)(a >> 16)));
  float b0 = __half2float(__ushort_as_half((unsigned short)(b & 0xffffu)));
  float b1 = __half2float(__ushort_as_half((unsigned short)(b >> 16)));
  return fmaf(a1, b1, fmaf(a0, b0, c));
#endif
}

// ---- e5m2 helpers ----
__device__ __forceinline__ unsigned enc2_e5m2(float a, float b) {
  unsigned ha = __half_as_ushort(__float2half(a));
  unsigned hb = __half_as_ushort(__float2half(b));
  ha = ((ha + 0x7fu + ((ha >> 8) & 1u)) >> 8) & 0xffu;
  hb = ((hb + 0x7fu + ((hb >> 8) & 1u)) >> 8) & 0xffu;
  return ha | (hb << 8);
}
__device__ __forceinline__ unsigned enc4_e5m2(float a, float b, float c, float d) {
  return enc2_e5m2(a, b) | (enc2_e5m2(c, d) << 16);
}

// ---------- K1: merged binfill (blocks < NFB) + project (blocks >= NFB) ----------
// binfill stages into 1024-entry (782 used) bin table; pair-scan (2 bins/thread).
__global__ __launch_bounds__(512)
void k_pb(const float* __restrict__ embeds, const float* __restrict__ W1,
          const float* __restrict__ b1, unsigned* __restrict__ P1p8,
          float* __restrict__ pool, int2* __restrict__ payTail,
          const int* __restrict__ src, const int* __restrict__ dst,
          const float* __restrict__ ew, const int* __restrict__ node_ids,
          int* __restrict__ binCursor, int2* __restrict__ stage,
          unsigned* __restrict__ h1p8) {
  __shared__ union {
    struct {
      int h[1024], cur[1024], adj[1024];    // 12 KB
      int wsum[8], woff[8];
      unsigned short binOf[EPB];            // 8 KB
      int2 buf[EPB];                        // 32 KB  (total ~52.1 KB)
    } f;
    struct {
      float sE[PR][D];              // 8 KB
      float sO[PR][D];              // 8 KB
    } p;
  } U;
  int t = threadIdx.x;
  if (blockIdx.x < NFB) {
    int lane = t & 63, wv = t >> 6;
    U.f.h[t] = 0; U.f.h[t + 512] = 0;
    __syncthreads();
    int base = blockIdx.x * EPB;
    int d_[EPB / 512], b_[EPB / 512];
#pragma unroll
    for (int i = 0; i < EPB / 512; ++i) {
      int e = base + i * 512 + t;
      int d = (e < NE) ? dst[e] : -1;
      d_[i] = d;
      b_[i] = (d >= 0) ? (d >> BSH2) : -1;
      if (d >= 0) atomicAdd(&U.f.h[b_[i]], 1);
    }
    __syncthreads();
    // pair-scan: thread t owns bins 2t, 2t+1
    int b0 = 2 * t, b1 = 2 * t + 1;
    int c0 = U.f.h[b0], c1 = U.f.h[b1];
    int v = c0 + c1;                          // wave-inclusive scan of pair sums
#pragma unroll
    for (int off = 1; off < 64; off <<= 1) {
      int x = __shfl_up(v, off);
      if (lane >= off) v += x;
    }
    if (lane == 63) U.f.wsum[wv] = v;
    __syncthreads();
    if (t == 0) {
      int a = 0;
#pragma unroll
      for (int i = 0; i < 8; ++i) { U.f.woff[i] = a; a += U.f.wsum[i]; }
    }
    __syncthreads();
    int inclP = v + U.f.woff[wv];
    int st1 = inclP - c1;                     // exclusive start of b1
    int st0 = st1 - c0;                       // exclusive start of b0
    U.f.cur[b0] = st0;
    U.f.cur[b1] = st1;
    int gb0 = (c0 > 0) ? atomicAdd(&binCursor[b0], c0) : 0;
    int gb1 = (c1 > 0) ? atomicAdd(&binCursor[b1], c1) : 0;
    U.f.adj[b0] = gb0 - st0;
    U.f.adj[b1] = gb1 - st1;
    __syncthreads();
    int total = U.f.woff[7] + U.f.wsum[7];
#pragma unroll
    for (int i = 0; i < EPB / 512; ++i) {
      int e = base + i * 512 + t;
      if (e < NE) {
        int s = src[e];
        unsigned uw = __float_as_uint(ew[e]);
        unsigned wb = (uw + 0x7fffu + ((uw >> 16) & 1u)) & 0xffff0000u;  // RN bf16
        int wid = node_ids[s];
        int dl = d_[i] & (BD2 - 1);
        int p = atomicAdd(&U.f.cur[b_[i]], 1);
        U.f.buf[p] = make_int2((int)(wb | (unsigned)wid), s | (dl << 17));
        U.f.binOf[p] = (unsigned short)b_[i];
      }
    }
    __syncthreads();
    for (int i = t; i < total; i += 512) {    // record-parallel coalesced flush
      int b = U.f.binOf[i];
      stage[(size_t)b * ST2 + (U.f.adj[b] + i)] = U.f.buf[i];
    }
  } else {
    int pb = blockIdx.x - NFB;
    if (pb == 0) {                 // zero pool + payTail + h1 guard rows
      for (int i = t; i < POOL_N; i += 512) pool[i] = 0.f;
      for (int i = t; i < PAY_TAIL; i += 512) payTail[i] = make_int2(0, 0);
      for (int i = t; i < 256 * 32; i += 512) h1p8[(size_t)NT * 32 + i] = 0u;
    }
    int row0 = pb * PR;
    for (int i = t; i < PR * D; i += 512) {
      int r = i >> 7, c = i & 127;
      int vv = row0 + r;
      U.p.sE[r][c] = (vv < V) ? embeds[(size_t)vv * D + c] : 0.f;
    }
    __syncthreads();
    int c = t & 127, rg = (t >> 7) * 4;      // 4 rows per thread
    float bd = b1[c];
    float acc[4];
#pragma unroll
    for (int r = 0; r < 4; ++r) acc[r] = bd;
#pragma unroll 4
    for (int k = 0; k < D; ++k) {
      float w = W1[k * D + c];
#pragma unroll
      for (int r = 0; r < 4; ++r) acc[r] = fmaf(U.p.sE[rg + r][k], w, acc[r]);
    }
#pragma unroll
    for (int r = 0; r < 4; ++r) U.p.sO[rg + r][c] = acc[r];
    __syncthreads();
    {
      int r = t >> 5, li = t & 31;           // 512 = 16 rows x 32
      int vv = row0 + r;
      if (vv < V)
        P1p8[(size_t)vv * 32 + li] =
            enc4_e5m2(U.p.sO[r][4 * li], U.p.sO[r][4 * li + 1],
                      U.p.sO[r][4 * li + 2], U.p.sO[r][4 * li + 3]);
    }
  }
}

// ---------- K2: per-bin counting-sort -> padded CSR, fused src-record emit ----
// 782 blocks, ONE private 128-dst bin each (~2K records): histogram pass +
// sort pass over own data only. ~31 KB LDS -> residency no longer LDS-bound.
__global__ __launch_bounds__(512)
void k_binsort(const int2* __restrict__ stage, const int* __restrict__ binCnt,
               int* __restrict__ rowD, int* __restrict__ cntD,
               int2* __restrict__ pay, int* __restrict__ sCursor,
               unsigned* __restrict__ stageS, float* __restrict__ poolC) {
  __shared__ int h2[BD2], cur2[BD2];
  __shared__ float invD[BD2];
  __shared__ int hS[512], curS[512];
  __shared__ int wsum2[2];
  __shared__ int sh_end;
  __shared__ int2 buf[BUF2];                // 23.5 KB
  int b = blockIdx.x, t = threadIdx.x;
  int lane = t & 63, wv = t >> 6;
  int cnt = binCnt[b];
  size_t sb = (size_t)b * ST2;
  int pb = b * PAY2;
  int dst0 = b << BSH2;
  int g0 = dst0 / NODES_PER_GRAPH;
  int bnd = (g0 + 1) * NODES_PER_GRAPH - dst0;
  int gg1 = g0 + 1; if (gg1 > B_GRAPHS - 1) gg1 = B_GRAPHS - 1;
  float sg0 = 0.f, sg1 = 0.f;
  if (t < BD2) h2[t] = 0;
  hS[t] = 0;
  __syncthreads();
  for (int i = t; i < cnt; i += 512) {
    int yv = stage[sb + i].y;
    atomicAdd(&h2[(yv >> 17) & 127], 1);
    atomicAdd(&hS[(yv & 0x1ffff) >> 8], 1);
  }
  __syncthreads();
  if (t < NBIN && hS[t] > 0) curS[t] = atomicAdd(&sCursor[t], hS[t]);
  int c = (t < BD2) ? h2[t] : 0;
  int pc = (c + 3) & ~3;                    // row padded to x4
  int v = (t < BD2) ? pc : 0;
#pragma unroll
  for (int off = 1; off < 64; off <<= 1) {  // wave-inclusive scan (2 waves used)
    int x = __shfl_up(v, off);
    if (lane >= off) v += x;
  }
  if (lane == 63 && wv < 2) wsum2[wv] = v;
  __syncthreads();
  if (t == 0) sh_end = wsum2[0] + wsum2[1];
  __syncthreads();
  if (t < BD2) {
    int myoff = v + (wv ? wsum2[0] : 0) - pc;   // exclusive padded offset
    invD[t] = (c > 0) ? (1.0f / (float)c) : 0.0f;
    cur2[t] = myoff;
    int n = dst0 + t;
    if (n < NT) { rowD[n] = pb + myoff; cntD[n] = c; }
  }
  __syncthreads();
  int end = sh_end + 24;                    // guard slots for gather prologue
  if (end > PAY2) end = PAY2;
  for (int i = t; i < end; i += 512) buf[i] = make_int2(0, 0);
  __syncthreads();
  for (int i = t; i < cnt; i += 512) {
    int2 r = stage[sb + i];
    int dl = (r.y >> 17) & 127;
    int srcn = r.y & 0x1ffff;
    float w = __uint_as_float((unsigned)r.x & 0xffff0000u);
    float wp = w * invD[dl];
    unsigned wh = (unsigned)__half_as_ushort(__float2half(wp));   // fp16 w'
    int p = atomicAdd(&cur2[dl], 1);
    buf[p] = make_int2((int)((wh << 16) | ((unsigned)r.x & 0xffffu)), srcn);
    // ---- fused layer-2 src-record emit (4B, clustered per src-bin) ----
    int g = (dl >= bnd) ? gg1 : g0;
    int sbin = srcn >> 8;
    int pos = atomicAdd(&curS[sbin], 1);
    stageS[(size_t)sbin * SS_STRIDE + pos] =
        (wh << 16) | ((unsigned)(srcn & 255) << 8) | (unsigned)g;
    if (dl >= bnd) sg1 += wp; else sg0 += wp;
  }
  __syncthreads();
  for (int i = t; i < end; i += 512) pay[pb + i] = buf[i];
#pragma unroll
  for (int off = 32; off > 0; off >>= 1) {
    sg0 += __shfl_down(sg0, off);
    sg1 += __shfl_down(sg1, off);
  }
  if (lane == 0) {
    if (sg0 != 0.f) atomicAdd(&poolC[g0], sg0);
    if (sg1 != 0.f) atomicAdd(&poolC[gg1], sg1);
  }
}

// ---- layer-1 row gather: depth-2 pipeline, v_perm decode, 4 edges/iter ----
// record word s = w'_fp16<<16 | wid(14b): index AND weight in one register.
__device__ __forceinline__ void consume2p(unsigned s, unsigned v,
                                          __half2& A01, __half2& A23) {
  unsigned wd  = __builtin_amdgcn_perm(s, 0u, 0x07060706u);  // [w',w']
  unsigned hp0 = __builtin_amdgcn_perm(v, 0u, 0x05000400u);  // dims d,d+1 (e5m2->f16)
  unsigned hp1 = __builtin_amdgcn_perm(v, 0u, 0x07000600u);  // dims d+2,d+3
  __half2 w2 = __builtin_bit_cast(__half2, wd);
  A01 = __hfma2(w2, __builtin_bit_cast(__half2, hp0), A01);
  A23 = __hfma2(w2, __builtin_bit_cast(__half2, hp1), A23);
}

__device__ __forceinline__ void gather_row2(const int2* __restrict__ pay,
                                            const unsigned* __restrict__ tab,
                                            int beg, int cnt, int li, int half,
                                            __half2& A01, __half2& A23) {
  int G = (cnt + 3) >> 2;                       // groups of 4 edges (rows padded)
  const int4* __restrict__ pp = (const int4*)(pay + beg);
  int4 qa = pp[0], qb = pp[1];
  unsigned sa = (unsigned)(half ? qa.z : qa.x);
  unsigned sb = (unsigned)(half ? qb.z : qb.x);
  unsigned va = tab[(size_t)(sa & 0xffffu) * 32 + li];
  unsigned vb = tab[(size_t)(sb & 0xffffu) * 32 + li];
  for (int g = 0; g < G; ++g) {
    int4 na = pp[2 * g + 2], nb = pp[2 * g + 3];   // <=2 int4 past row: guarded
    unsigned sna = (unsigned)(half ? na.z : na.x);
    unsigned snb = (unsigned)(half ? nb.z : nb.x);
    unsigned wa = tab[(size_t)(sna & 0xffffu) * 32 + li];
    unsigned wb = tab[(size_t)(snb & 0xffffu) * 32 + li];
    consume2p(sa, va, A01, A23);
    consume2p(sb, vb, A01, A23);
    sa = sna; sb = snb; va = wa; vb = wb;
  }
}

// ---------- K3: layer-1 aggregate (w' folded mean) + leaky -> h1p8 ----------
#define NPW1 10
__global__ void k_agg1(const int2* __restrict__ pay,
                       const int* __restrict__ rowD, const int* __restrict__ cntD,
                       const unsigned* __restrict__ P1p8,
                       unsigned* __restrict__ h1p8) {
  int w = threadIdx.x >> 6, lane = threadIdx.x & 63;
  int li = lane & 31, half = lane >> 5;
  int nbase = blockIdx.x * (4 * NPW1) + w * NPW1;
  for (int i = 0; i < NPW1; ++i) {
    int n = nbase + i;
    int beg = __builtin_amdgcn_readfirstlane(rowD[n]);
    int cnt = __builtin_amdgcn_readfirstlane(cntD[n]);
    __half2 A01 = __half2half2(__float2half(0.f));
    __half2 A23 = A01;
    gather_row2(pay, P1p8, beg, cnt, li, half, A01, A23);
    float2 f01 = __half22float2(A01);
    float2 f23 = __half22float2(A23);
    float a0 = f01.x, a1 = f01.y, a2 = f23.x, a3 = f23.y;
    a0 += __shfl_down(a0, 32);
    a1 += __shfl_down(a1, 32);
    a2 += __shfl_down(a2, 32);
    a3 += __shfl_down(a3, 32);
    if (lane < 32) {
      float x0 = a0, x1 = a1, x2 = a2, x3 = a3;  // w'=w/deg -> already the mean
      x0 = (x0 > 0.f) ? x0 : 0.01f * x0;    // leaky_relu(0)=0 keeps deg==0 rows 0
      x1 = (x1 > 0.f) ? x1 : 0.01f * x1;
      x2 = (x2 > 0.f) ? x2 : 0.01f * x2;
      x3 = (x3 > 0.f) ? x3 : 0.01f * x3;
      h1p8[(size_t)n * 32 + li] = enc4_e5m2(x0, x1, x2, x3);
    }
  }
}

// ---------- K4: per-src-bin C-build + [50x256]x[256x128] mini-GEMM ----------
__global__ __launch_bounds__(512)
void k_cpool(const unsigned* __restrict__ stageS, const int* __restrict__ sCnt,
             const unsigned* __restrict__ h1p8, float* __restrict__ part) {
  __shared__ float Cl[256 * B_GRAPHS];          // [sl][g]  51.2 KB
  __shared__ unsigned Cl2[B_GRAPHS * 128];      // [g][sp]  packed half2, 25.6 KB
  int b = blockIdx.x, t = threadIdx.x;
  for (int i = t; i < 256 * B_GRAPHS; i += 512) Cl[i] = 0.f;
  __syncthreads();
  int cnt = sCnt[b];
  const unsigned* __restrict__ sp_ = stageS + (size_t)b * SS_STRIDE;
  for (int i = t; i < cnt; i += 512) {
    unsigned r = sp_[i];
    int g = (int)(r & 63u);
    int sl = (int)((r >> 8) & 255u);
    float wp = __half2float(__ushort_as_half((unsigned short)(r >> 16)));
    atomicAdd(&Cl[sl * B_GRAPHS + g], wp);
  }
  __syncthreads();
  for (int i = t; i < B_GRAPHS * 128; i += 512) {   // pack: Cl2[g][sp]
    int g = i >> 7, sp = i & 127;
    float lo = Cl[(2 * sp) * B_GRAPHS + g];
    float hi = Cl[(2 * sp + 1) * B_GRAPHS + g];
    __half2 h = __floats2half2_rn(lo, hi);
    Cl2[i] = __builtin_bit_cast(unsigned, h);
  }
  __syncthreads();
  int d = t & 127, gq = t >> 7;                 // 4 graph-groups
  int row0 = b * 256;
  const unsigned* __restrict__ hp = h1p8 + ((size_t)row0 * 32 + (d >> 2));
  int sh = 8 * (d & 3);
  float acc[13];
#pragma unroll
  for (int j = 0; j < 13; ++j) acc[j] = 0.f;
  for (int s4 = 0; s4 < 32; ++s4) {             // 4 sp (8 rows) per iter
    unsigned pk[4];
#pragma unroll
    for (int u = 0; u < 4; ++u) {
      unsigned v0 = hp[0], v1 = hp[32];         // rows 2sp, 2sp+1
      hp += 64;
      pk[u] = (((v0 >> sh) & 0xffu) << 8) | (((v1 >> sh) & 0xffu) << 24);
    }
#pragma unroll
    for (int j = 0; j < 13; ++j) {
      int g = gq + 4 * j;
      if (g < B_GRAPHS) {
        uint4 c4 = *(const uint4*)&Cl2[g * 128 + 4 * s4];   // ds_read_b128
        acc[j] = dot2acc(pk[0], c4.x, acc[j]);
        acc[j] = dot2acc(pk[1], c4.y, acc[j]);
        acc[j] = dot2acc(pk[2], c4.z, acc[j]);
        acc[j] = dot2acc(pk[3], c4.w, acc[j]);
      }
    }
  }
  float* __restrict__ pb = part + (size_t)b * (B_GRAPHS * D);
#pragma unroll
  for (int j = 0; j < 13; ++j) {
    int g = gq + 4 * j;
    if (g < B_GRAPHS) pb[g * D + d] = acc[j];
  }
}

// ---------- K5: reduce 391 partial pool sets -> pool (no atomics) ----------
__global__ __launch_bounds__(256)
void k_reduce(const float* __restrict__ part, float* __restrict__ pool) {
  __shared__ float red[3][64];
  int t = threadIdx.x;
  int c = blockIdx.x * 64 + (t & 63);
  int q = t >> 6;
  int p0 = (q * NPART) >> 2, p1 = ((q + 1) * NPART) >> 2;
  float s = 0.f;
#pragma unroll 8
  for (int p = p0; p < p1; ++p) s += part[(size_t)p * (B_GRAPHS * D) + c];
  if (q) red[q - 1][t & 63] = s;
  __syncthreads();
  if (!q) pool[c] = s + red[0][t & 63] + red[1][t & 63] + red[2][t & 63];
}

// ---------- K6: head ----------
__global__ void k_final(const float* __restrict__ poolS, const float* __restrict__ poolC,
                        const float* __restrict__ W2, const float* __restrict__ b2,
                        const float* __restrict__ W_out, const float* __restrict__ b_out,
                        const float* __restrict__ y, float* __restrict__ out) {
  __shared__ float w2o[D];
  __shared__ float s2oArr[D];
  __shared__ float s2o_sh;
  __shared__ float logits[64];
  int t = threadIdx.x;                     // 256 threads = 4 waves
  int w = t >> 6, lane = t & 63;
  if (t < D) {
    float acc = 0.f;
    for (int d = 0; d < D; ++d) acc = fmaf(W2[t * D + d], W_out[d], acc);
    w2o[t] = acc;
  } else {
    int j = t - D;
    s2oArr[j] = b2[j] * W_out[j];
  }
  __syncthreads();
  if (t < 64) {
    float v = s2oArr[lane] + s2oArr[64 + lane];
#pragma unroll
    for (int off = 32; off > 0; off >>= 1) v += __shfl_down(v, off);
    if (lane == 0) s2o_sh = v;
  }
  __syncthreads();
  float s2o = s2o_sh;
  float bout = b_out[0];
  const float invN = 1.0f / (float)NODES_PER_GRAPH;
  for (int g = w; g < B_GRAPHS; g += 4) {
    float v = poolS[g * D + lane] * w2o[lane]
            + poolS[g * D + 64 + lane] * w2o[64 + lane];
#pragma unroll
    for (int off = 32; off > 0; off >>= 1) v += __shfl_down(v, off);
    if (lane == 0) {
      float l = v * invN + poolC[g] * invN * s2o + bout;
      logits[g] = l;
      out[1 + g] = 1.0f / (1.0f + expf(-l));         // y_pred
    }
  }
  __syncthreads();
  if (t < 64) {
    float term = 0.f;
    if (lane < B_GRAPHS) {
      float l = logits[lane];
      term = fmaxf(l, 0.f) - l * y[lane] + log1pf(expf(-fabsf(l)));
    }
#pragma unroll
    for (int off = 32; off > 0; off >>= 1) term += __shfl_down(term, off);
    if (lane == 0) out[0] = term / (float)B_GRAPHS;  // loss
  }
}

extern "C" void kernel_launch(void* const* d_in, const int* in_sizes, int n_in,
                              void* d_out, int out_size, void* d_ws, size_t ws_size,
                              hipStream_t stream) {
  const int*   node_ids = (const int*)d_in[0];
  const int*   src      = (const int*)d_in[1];
  const int*   dst      = (const int*)d_in[2];
  const float* ew       = (const float*)d_in[3];
  const float* y        = (const float*)d_in[4];
  const float* embeds   = (const float*)d_in[5];
  const float* W1       = (const float*)d_in[6];
  const float* b1       = (const float*)d_in[7];
  const float* W2       = (const float*)d_in[8];
  const float* b2       = (const float*)d_in[9];
  const float* W_out    = (const float*)d_in[10];
  const float* b_out    = (const float*)d_in[11];
  float* out = (float*)d_out;
  (void)in_sizes; (void)n_in; (void)out_size; (void)ws_size;

  char* ws = (char*)d_ws;
  size_t off = 0;
  auto alloc = [&](size_t bytes) {
    size_t r = off;
    off = (off + bytes + 511) & ~(size_t)511;
    return r;
  };
  size_t o_binCur = alloc(2048 * 4);                              // binCursor[1024] + sCursor[512]
  size_t o_pool   = alloc((size_t)POOL_N * 4);
  size_t o_rowD   = alloc((size_t)(NT + 1) * 4);
  size_t o_cntD   = alloc((size_t)NT * 4);
  size_t o_P1p8   = alloc((size_t)V * 32 * 4);                    // 1.92 MB
  size_t o_h1p8   = alloc((size_t)(NT + 256) * 32 * 4);           // 12.8 MB + guard
  size_t o_stage  = alloc((size_t)NBIN2 * ST2 * 8);               // 15.2 MB
  size_t o_pay    = alloc(((size_t)NBIN2 * PAY2 + PAY_TAIL) * 8); // 18.4 MB
  size_t o_stageS = alloc((size_t)NBIN * SS_STRIDE * 4);          // 7.2 MB

  int*      binCursor= (int*)(ws + o_binCur);
  int*      sCursor  = binCursor + 1024;
  float*    pool     = (float*)(ws + o_pool);
  int*      rowD     = (int*)(ws + o_rowD);
  int*      cntD     = (int*)(ws + o_cntD);
  unsigned* P1p8     = (unsigned*)(ws + o_P1p8);
  unsigned* h1p8     = (unsigned*)(ws + o_h1p8);
  int2*     stage    = (int2*)(ws + o_stage);
  int2*     pay      = (int2*)(ws + o_pay);
  unsigned* stageS   = (unsigned*)(ws + o_stageS);
  int2*     payTail  = pay + (size_t)NBIN2 * PAY2;
  // pool partials alias stage (dead after k_binsort; k_cpool runs after k_agg1)
  float*    part     = (float*)(ws + o_stage);                    // 10.0 MB < 15.2 MB

  (void)hipMemsetAsync(binCursor, 0, 2048 * 4, stream);
  k_pb<<<NFB + PROJ_BLOCKS, 512, 0, stream>>>(embeds, W1, b1, P1p8, pool, payTail,
                                              src, dst, ew, node_ids, binCursor, stage,
                                              h1p8);
  k_binsort<<<NBIN2, 512, 0, stream>>>(stage, binCursor, rowD, cntD, pay,
                                       sCursor, stageS, pool + B_GRAPHS * D);
  k_agg1<<<NT / (4 * NPW1), 256, 0, stream>>>(pay, rowD, cntD, P1p8, h1p8);
  k_cpool<<<NBIN, 512, 0, stream>>>(stageS, sCursor, h1p8, part);
  k_reduce<<<B_GRAPHS * D / 64, 256, 0, stream>>>(part, pool);
  k_final<<<1, 256, 0, stream>>>(pool, pool + B_GRAPHS * D, W2, b2, W_out, b_out, y, out);
}

// Round 8
// 262.819 us; speedup vs baseline: 1.1575x; 1.1575x over previous
//
#include <hip/hip_runtime.h>
#include <hip/hip_fp16.h>
#include <math.h>

#define NT 100000
#define B_GRAPHS 50
#define NE 1600000
#define V 15000
#define D 128
#define NODES_PER_GRAPH (NT / B_GRAPHS)   // 2000

#define POOL_N (B_GRAPHS * D + B_GRAPHS)  // 6450

#define BSH 8
#define BIN_DSTS 256
#define NBIN ((NT + BIN_DSTS - 1) / BIN_DSTS)   // 391
#define SLACK (3 * BIN_DSTS)                    // 768 (worst-case row padding)
#define EPB 4096                                // edges per binfill block
#define NFB ((NE + EPB - 1) / EPB)              // 391
#define BUF_SORT 5632                           // per-bin LDS record cap
#define STAGE_STRIDE 4608                       // max bin cnt ~4300 (8 sigma); = 9*512
#define PAY_STRIDE (STAGE_STRIDE + SLACK)       // 5376, x4 aligned
#define PAY_TAIL 512
#define PR 16
#define PROJ_BLOCKS ((V + PR - 1) / PR)         // 938
#define RPT 9                                   // stage records per thread (9*512=4608)

// ---- layer-2 src-binned contraction ----
// pool[g][d] = sum_k C[k][g] * h1[k][d], C[k][g] = sum of w' over edges
// (src=k, dst in graph g). Src-records (4B: w'_fp16<<16 | srcLocal<<8 | g)
// are emitted directly by k_binsort into 391 src-bins; k_cpool builds
// Cl[256][50] in LDS per bin and contracts against the bin's 256
// contiguous h1 rows with v_dot2_f32_f16.
#define SS_STRIDE 4608               // same distribution as dst bins
#define NPART NBIN                   // 391 pool partials

typedef _Float16 half2_t __attribute__((ext_vector_type(2)));

#if defined(__has_builtin)
#if __has_builtin(__builtin_amdgcn_fdot2)
#define HAVE_FDOT2 1
#endif
#endif

__device__ __forceinline__ float dot2acc(unsigned a, unsigned b, float c) {
#ifdef HAVE_FDOT2
  return __builtin_amdgcn_fdot2(__builtin_bit_cast(half2_t, a),
                                __builtin_bit_cast(half2_t, b), c, false);
#else
  float a0 = __half2float(__ushort_as_half((unsigned short)(a & 0xffffu)));
  float a1 = __half2float(__ushort_as_half((unsigned short)(a >> 16)));
  float b0 = __half2float(__ushort_as_half((unsigned short)(b & 0xffffu)));
  float b1 = __half2float(__ushort_as_half((unsigned short)(b >> 16)));
  return fmaf(a1, b1, fmaf(a0, b0, c));
#endif
}

// ---- e5m2 helpers ----
__device__ __forceinline__ unsigned enc2_e5m2(float a, float b) {
  unsigned ha = __half_as_ushort(__float2half(a));
  unsigned hb = __half_as_ushort(__float2half(b));
  ha = ((ha + 0x7fu + ((ha >> 8) & 1u)) >> 8) & 0xffu;
  hb = ((hb + 0x7fu + ((hb >> 8) & 1u)) >> 8) & 0xffu;
  return ha | (hb << 8);
}
__device__ __forceinline__ unsigned enc4_e5m2(float a, float b, float c, float d) {
  return enc2_e5m2(a, b) | (enc2_e5m2(c, d) << 16);
}

// ---------- K1: merged binfill (blocks < NFB) + project (blocks >= NFB) ----------
// Binfill prefetches src/ew/node_ids alongside dst so the scatter phase is
// register-only (the node_ids gathers complete under the scan barriers).
__global__ __launch_bounds__(512)
void k_pb(const float* __restrict__ embeds, const float* __restrict__ W1,
          const float* __restrict__ b1, unsigned* __restrict__ P1p8,
          float* __restrict__ pool, int2* __restrict__ payTail,
          const int* __restrict__ src, const int* __restrict__ dst,
          const float* __restrict__ ew, const int* __restrict__ node_ids,
          int* __restrict__ binCursor, int2* __restrict__ stage,
          unsigned* __restrict__ h1p8) {
  __shared__ union {
    struct {
      int h[512], sc[512], gbase[512], cur[512];
      int wsum[8], woff[8];
      unsigned short binOf[EPB];    // 8 KB
      int2 buf[EPB];                // 32 KB
    } f;
    struct {
      float sE[PR][D];              // 8 KB
      float sO[PR][D];              // 8 KB
    } p;
  } U;
  int t = threadIdx.x;
  if (blockIdx.x < NFB) {
    int lane = t & 63, wv = t >> 6;
    U.f.h[t] = 0;
    __syncthreads();
    int base = blockIdx.x * EPB;
    int d_[EPB / 512], b_[EPB / 512], s_[EPB / 512], wid_[EPB / 512];
    unsigned uw_[EPB / 512];
#pragma unroll
    for (int i = 0; i < EPB / 512; ++i) {       // phase A: all streams coalesced
      int e = base + i * 512 + t;
      int ok = (e < NE);
      int d = ok ? dst[e] : -1;
      d_[i] = d;
      b_[i] = (d >= 0) ? (d >> BSH) : -1;
      s_[i] = ok ? src[e] : 0;
      uw_[i] = ok ? __float_as_uint(ew[e]) : 0u;
      if (d >= 0) atomicAdd(&U.f.h[b_[i]], 1);
    }
#pragma unroll
    for (int i = 0; i < EPB / 512; ++i)         // issue gathers before the scan
      wid_[i] = (d_[i] >= 0) ? node_ids[s_[i]] : 0;
    __syncthreads();
    int c = U.f.h[t];
    int v = c;                                // wave-inclusive scan
#pragma unroll
    for (int off = 1; off < 64; off <<= 1) {
      int x = __shfl_up(v, off);
      if (lane >= off) v += x;
    }
    if (lane == 63) U.f.wsum[wv] = v;
    __syncthreads();
    if (t == 0) {
      int a = 0;
#pragma unroll
      for (int i = 0; i < 8; ++i) { U.f.woff[i] = a; a += U.f.wsum[i]; }
    }
    __syncthreads();
    int incl = v + U.f.woff[wv];
    U.f.sc[t] = incl;
    U.f.cur[t] = incl - c;
    if (t < NBIN && c > 0) U.f.gbase[t] = atomicAdd(&binCursor[t], c);
    __syncthreads();
    int total = U.f.sc[511];
#pragma unroll
    for (int i = 0; i < EPB / 512; ++i) {       // phase C: register-only scatter
      if (d_[i] >= 0) {
        unsigned uw = uw_[i];
        unsigned wb = (uw + 0x7fffu + ((uw >> 16) & 1u)) & 0xffff0000u;  // RN bf16
        int dl = d_[i] & (BIN_DSTS - 1);
        int p = atomicAdd(&U.f.cur[b_[i]], 1);
        U.f.buf[p] = make_int2((int)(wb | (unsigned)wid_[i]), s_[i] | (dl << 17));
        U.f.binOf[p] = (unsigned short)b_[i];
      }
    }
    __syncthreads();
    for (int i = t; i < total; i += 512) {    // record-parallel coalesced flush
      int b = U.f.binOf[i];
      int local = i - (U.f.sc[b] - U.f.h[b]);
      stage[(size_t)b * STAGE_STRIDE + U.f.gbase[b] + local] = U.f.buf[i];
    }
  } else {
    int pb = blockIdx.x - NFB;
    if (pb == 0) {                 // zero pool + payTail + h1 guard rows
      for (int i = t; i < POOL_N; i += 512) pool[i] = 0.f;
      for (int i = t; i < PAY_TAIL; i += 512) payTail[i] = make_int2(0, 0);
      for (int i = t; i < 256 * 32; i += 512) h1p8[(size_t)NT * 32 + i] = 0u;
    }
    int row0 = pb * PR;
    for (int i = t; i < PR * D; i += 512) {
      int r = i >> 7, c = i & 127;
      int vv = row0 + r;
      U.p.sE[r][c] = (vv < V) ? embeds[(size_t)vv * D + c] : 0.f;
    }
    __syncthreads();
    int c = t & 127, rg = (t >> 7) * 4;      // 4 rows per thread
    float bd = b1[c];
    float acc[4];
#pragma unroll
    for (int r = 0; r < 4; ++r) acc[r] = bd;
#pragma unroll 4
    for (int k = 0; k < D; ++k) {
      float w = W1[k * D + c];
#pragma unroll
      for (int r = 0; r < 4; ++r) acc[r] = fmaf(U.p.sE[rg + r][k], w, acc[r]);
    }
#pragma unroll
    for (int r = 0; r < 4; ++r) U.p.sO[rg + r][c] = acc[r];
    __syncthreads();
    {
      int r = t >> 5, li = t & 31;           // 512 = 16 rows x 32
      int vv = row0 + r;
      if (vv < V)
        P1p8[(size_t)vv * 32 + li] =
            enc4_e5m2(U.p.sO[r][4 * li], U.p.sO[r][4 * li + 1],
                      U.p.sO[r][4 * li + 2], U.p.sO[r][4 * li + 3]);
    }
  }
}

// ---------- K2: per-bin counting-sort -> padded CSR, fused src-record emit ----------
// The bin's records are register-staged ONCE (<=9/thread, all loads in flight
// together); histogram and sort passes both run from registers, removing the
// second full-latency global sweep of stage.
__global__ __launch_bounds__(512)
void k_binsort(const int2* __restrict__ stage, const int* __restrict__ binCnt,
               int* __restrict__ rowD, int* __restrict__ cntD,
               int2* __restrict__ pay, int* __restrict__ sCursor,
               unsigned* __restrict__ stageS, float* __restrict__ poolC) {
  __shared__ int h2[BIN_DSTS], cur2[BIN_DSTS];
  __shared__ float invD[BIN_DSTS];
  __shared__ int hS[512], curS[512];
  __shared__ int wsum4[4], woff4[4];
  __shared__ int sh_end;
  __shared__ int2 buf[BUF_SORT];            // 44 KB
  int b = blockIdx.x, t = threadIdx.x;
  int lane = t & 63, wv = t >> 6;
  int cnt = binCnt[b];
  int sb = b * STAGE_STRIDE;
  int pb = b * PAY_STRIDE;
  int dst0 = b << BSH;
  int g0 = dst0 / NODES_PER_GRAPH;
  int bnd = (g0 + 1) * NODES_PER_GRAPH - dst0;
  int gg1 = g0 + 1; if (gg1 > B_GRAPHS - 1) gg1 = B_GRAPHS - 1;
  float sg0 = 0.f, sg1 = 0.f;
  if (t < BIN_DSTS) h2[t] = 0;
  hS[t] = 0;
  __syncthreads();
  // register-stage: thread t owns records t, t+512, ..., t+8*512
  int2 rec[RPT];
#pragma unroll
  for (int r = 0; r < RPT; ++r) {
    int i = t + r * 512;
    rec[r] = (i < cnt) ? stage[sb + i] : make_int2(0, 0);
  }
#pragma unroll
  for (int r = 0; r < RPT; ++r) {
    if (t + r * 512 < cnt) {
      int yv = rec[r].y;
      atomicAdd(&h2[(yv >> 17) & 255], 1);
      atomicAdd(&hS[(yv & 0x1ffff) >> 8], 1);
    }
  }
  __syncthreads();
  if (t < NBIN && hS[t] > 0) curS[t] = atomicAdd(&sCursor[t], hS[t]);
  int c = (t < BIN_DSTS) ? h2[t] : 0;
  int pc = (c + 3) & ~3;                    // row padded to x4
  int v = (t < BIN_DSTS) ? pc : 0;
#pragma unroll
  for (int off = 1; off < 64; off <<= 1) {  // wave-inclusive scan
    int x = __shfl_up(v, off);
    if (lane >= off) v += x;
  }
  if (lane == 63 && wv < 4) wsum4[wv] = v;
  __syncthreads();
  if (t == 0) {
    int a = 0;
#pragma unroll
    for (int i = 0; i < 4; ++i) { woff4[i] = a; a += wsum4[i]; }
    sh_end = a;
  }
  __syncthreads();
  if (t < BIN_DSTS) {
    int myoff = v + woff4[wv] - pc;
    invD[t] = (c > 0) ? (1.0f / (float)c) : 0.0f;
    cur2[t] = myoff;
    int n = dst0 + t;
    if (n < NT) { rowD[n] = pb + myoff; cntD[n] = c; }
  }
  __syncthreads();
  int end = sh_end + 24;                    // guard slots for gather prologue
  if (end > PAY_STRIDE) end = PAY_STRIDE;
  for (int i = t; i < end; i += 512) buf[i] = make_int2(0, 0);
  __syncthreads();
#pragma unroll
  for (int r = 0; r < RPT; ++r) {
    if (t + r * 512 >= cnt) continue;
    int2 rr = rec[r];
    int dl = (rr.y >> 17) & 255;
    int srcn = rr.y & 0x1ffff;
    float w = __uint_as_float((unsigned)rr.x & 0xffff0000u);
    float wp = w * invD[dl];
    unsigned wh = (unsigned)__half_as_ushort(__float2half(wp));   // fp16 w'
    int p = atomicAdd(&cur2[dl], 1);
    buf[p] = make_int2((int)((wh << 16) | ((unsigned)rr.x & 0xffffu)), srcn);
    // ---- fused layer-2 src-record emit (4B, clustered per src-bin) ----
    int g = (dl >= bnd) ? gg1 : g0;
    int sbin = srcn >> 8;
    int pos = atomicAdd(&curS[sbin], 1);
    stageS[(size_t)sbin * SS_STRIDE + pos] =
        (wh << 16) | ((unsigned)(srcn & 255) << 8) | (unsigned)g;
    if (dl >= bnd) sg1 += wp; else sg0 += wp;
  }
  __syncthreads();
  for (int i = t; i < end; i += 512) pay[pb + i] = buf[i];
#pragma unroll
  for (int off = 32; off > 0; off >>= 1) {
    sg0 += __shfl_down(sg0, off);
    sg1 += __shfl_down(sg1, off);
  }
  if (lane == 0) {
    if (sg0 != 0.f) atomicAdd(&poolC[g0], sg0);
    if (sg1 != 0.f) atomicAdd(&poolC[gg1], sg1);
  }
}

// ---- layer-1 row gather: depth-2 pipeline, v_perm decode, 4 edges/iter ----
// record word s = w'_fp16<<16 | wid(14b): index AND weight in one register.
__device__ __forceinline__ void consume2p(unsigned s, unsigned v,
                                          __half2& A01, __half2& A23) {
  unsigned wd  = __builtin_amdgcn_perm(s, 0u, 0x07060706u);  // [w',w']
  unsigned hp0 = __builtin_amdgcn_perm(v, 0u, 0x05000400u);  // dims d,d+1 (e5m2->f16)
  unsigned hp1 = __builtin_amdgcn_perm(v, 0u, 0x07000600u);  // dims d+2,d+3
  __half2 w2 = __builtin_bit_cast(__half2, wd);
  A01 = __hfma2(w2, __builtin_bit_cast(__half2, hp0), A01);
  A23 = __hfma2(w2, __builtin_bit_cast(__half2, hp1), A23);
}

__device__ __forceinline__ void gather_row2(const int2* __restrict__ pay,
                                            const unsigned* __restrict__ tab,
                                            int beg, int cnt, int li, int half,
                                            __half2& A01, __half2& A23) {
  int G = (cnt + 3) >> 2;                       // groups of 4 edges (rows padded)
  const int4* __restrict__ pp = (const int4*)(pay + beg);
  int4 qa = pp[0], qb = pp[1];
  unsigned sa = (unsigned)(half ? qa.z : qa.x);
  unsigned sb = (unsigned)(half ? qb.z : qb.x);
  unsigned va = tab[(size_t)(sa & 0xffffu) * 32 + li];
  unsigned vb = tab[(size_t)(sb & 0xffffu) * 32 + li];
  for (int g = 0; g < G; ++g) {
    int4 na = pp[2 * g + 2], nb = pp[2 * g + 3];   // <=2 int4 past row: guarded
    unsigned sna = (unsigned)(half ? na.z : na.x);
    unsigned snb = (unsigned)(half ? nb.z : nb.x);
    unsigned wa = tab[(size_t)(sna & 0xffffu) * 32 + li];
    unsigned wb = tab[(size_t)(snb & 0xffffu) * 32 + li];
    consume2p(sa, va, A01, A23);
    consume2p(sb, vb, A01, A23);
    sa = sna; sb = snb; va = wa; vb = wb;
  }
}

// ---------- K3: layer-1 aggregate (w' folded mean) + leaky -> h1p8 ----------
#define NPW1 10
__global__ void k_agg1(const int2* __restrict__ pay,
                       const int* __restrict__ rowD, const int* __restrict__ cntD,
                       const unsigned* __restrict__ P1p8,
                       unsigned* __restrict__ h1p8) {
  int w = threadIdx.x >> 6, lane = threadIdx.x & 63;
  int li = lane & 31, half = lane >> 5;
  int nbase = blockIdx.x * (4 * NPW1) + w * NPW1;
  for (int i = 0; i < NPW1; ++i) {
    int n = nbase + i;
    int beg = __builtin_amdgcn_readfirstlane(rowD[n]);
    int cnt = __builtin_amdgcn_readfirstlane(cntD[n]);
    __half2 A01 = __half2half2(__float2half(0.f));
    __half2 A23 = A01;
    gather_row2(pay, P1p8, beg, cnt, li, half, A01, A23);
    float2 f01 = __half22float2(A01);
    float2 f23 = __half22float2(A23);
    float a0 = f01.x, a1 = f01.y, a2 = f23.x, a3 = f23.y;
    a0 += __shfl_down(a0, 32);
    a1 += __shfl_down(a1, 32);
    a2 += __shfl_down(a2, 32);
    a3 += __shfl_down(a3, 32);
    if (lane < 32) {
      float x0 = a0, x1 = a1, x2 = a2, x3 = a3;  // w'=w/deg -> already the mean
      x0 = (x0 > 0.f) ? x0 : 0.01f * x0;    // leaky_relu(0)=0 keeps deg==0 rows 0
      x1 = (x1 > 0.f) ? x1 : 0.01f * x1;
      x2 = (x2 > 0.f) ? x2 : 0.01f * x2;
      x3 = (x3 > 0.f) ? x3 : 0.01f * x3;
      h1p8[(size_t)n * 32 + li] = enc4_e5m2(x0, x1, x2, x3);
    }
  }
}

// ---------- K4: per-src-bin C-build + [50x256]x[256x128] mini-GEMM ----------
__global__ __launch_bounds__(512)
void k_cpool(const unsigned* __restrict__ stageS, const int* __restrict__ sCnt,
             const unsigned* __restrict__ h1p8, float* __restrict__ part) {
  __shared__ float Cl[256 * B_GRAPHS];          // [sl][g]  51.2 KB
  __shared__ unsigned Cl2[B_GRAPHS * 128];      // [g][sp]  packed half2, 25.6 KB
  int b = blockIdx.x, t = threadIdx.x;
  for (int i = t; i < 256 * B_GRAPHS; i += 512) Cl[i] = 0.f;
  __syncthreads();
  int cnt = sCnt[b];
  const unsigned* __restrict__ sp_ = stageS + (size_t)b * SS_STRIDE;
  for (int i = t; i < cnt; i += 512) {
    unsigned r = sp_[i];
    int g = (int)(r & 63u);
    int sl = (int)((r >> 8) & 255u);
    float wp = __half2float(__ushort_as_half((unsigned short)(r >> 16)));
    atomicAdd(&Cl[sl * B_GRAPHS + g], wp);
  }
  __syncthreads();
  for (int i = t; i < B_GRAPHS * 128; i += 512) {   // pack: Cl2[g][sp]
    int g = i >> 7, sp = i & 127;
    float lo = Cl[(2 * sp) * B_GRAPHS + g];
    float hi = Cl[(2 * sp + 1) * B_GRAPHS + g];
    __half2 h = __floats2half2_rn(lo, hi);
    Cl2[i] = __builtin_bit_cast(unsigned, h);
  }
  __syncthreads();
  int d = t & 127, gq = t >> 7;                 // 4 graph-groups
  int row0 = b * 256;
  const unsigned* __restrict__ hp = h1p8 + ((size_t)row0 * 32 + (d >> 2));
  int sh = 8 * (d & 3);
  float acc[13];
#pragma unroll
  for (int j = 0; j < 13; ++j) acc[j] = 0.f;
  for (int s4 = 0; s4 < 32; ++s4) {             // 4 sp (8 rows) per iter
    unsigned pk[4];
#pragma unroll
    for (int u = 0; u < 4; ++u) {
      unsigned v0 = hp[0], v1 = hp[32];         // rows 2sp, 2sp+1
      hp += 64;
      pk[u] = (((v0 >> sh) & 0xffu) << 8) | (((v1 >> sh) & 0xffu) << 24);
    }
#pragma unroll
    for (int j = 0; j < 13; ++j) {
      int g = gq + 4 * j;
      if (g < B_GRAPHS) {
        uint4 c4 = *(const uint4*)&Cl2[g * 128 + 4 * s4];   // ds_read_b128
        acc[j] = dot2acc(pk[0], c4.x, acc[j]);
        acc[j] = dot2acc(pk[1], c4.y, acc[j]);
        acc[j] = dot2acc(pk[2], c4.z, acc[j]);
        acc[j] = dot2acc(pk[3], c4.w, acc[j]);
      }
    }
  }
  float* __restrict__ pb = part + (size_t)b * (B_GRAPHS * D);
#pragma unroll
  for (int j = 0; j < 13; ++j) {
    int g = gq + 4 * j;
    if (g < B_GRAPHS) pb[g * D + d] = acc[j];
  }
}

// ---------- K5: reduce 391 partial pool sets -> pool (no atomics) ----------
__global__ __launch_bounds__(256)
void k_reduce(const float* __restrict__ part, float* __restrict__ pool) {
  __shared__ float red[3][64];
  int t = threadIdx.x;
  int c = blockIdx.x * 64 + (t & 63);
  int q = t >> 6;
  int p0 = (q * NPART) >> 2, p1 = ((q + 1) * NPART) >> 2;
  float s = 0.f;
#pragma unroll 8
  for (int p = p0; p < p1; ++p) s += part[(size_t)p * (B_GRAPHS * D) + c];
  if (q) red[q - 1][t & 63] = s;
  __syncthreads();
  if (!q) pool[c] = s + red[0][t & 63] + red[1][t & 63] + red[2][t & 63];
}

// ---------- K6: head ----------
__global__ void k_final(const float* __restrict__ poolS, const float* __restrict__ poolC,
                        const float* __restrict__ W2, const float* __restrict__ b2,
                        const float* __restrict__ W_out, const float* __restrict__ b_out,
                        const float* __restrict__ y, float* __restrict__ out) {
  __shared__ float w2o[D];
  __shared__ float s2oArr[D];
  __shared__ float s2o_sh;
  __shared__ float logits[64];
  int t = threadIdx.x;                     // 256 threads = 4 waves
  int w = t >> 6, lane = t & 63;
  if (t < D) {
    float acc = 0.f;
    for (int d = 0; d < D; ++d) acc = fmaf(W2[t * D + d], W_out[d], acc);
    w2o[t] = acc;
  } else {
    int j = t - D;
    s2oArr[j] = b2[j] * W_out[j];
  }
  __syncthreads();
  if (t < 64) {
    float v = s2oArr[lane] + s2oArr[64 + lane];
#pragma unroll
    for (int off = 32; off > 0; off >>= 1) v += __shfl_down(v, off);
    if (lane == 0) s2o_sh = v;
  }
  __syncthreads();
  float s2o = s2o_sh;
  float bout = b_out[0];
  const float invN = 1.0f / (float)NODES_PER_GRAPH;
  for (int g = w; g < B_GRAPHS; g += 4) {
    float v = poolS[g * D + lane] * w2o[lane]
            + poolS[g * D + 64 + lane] * w2o[64 + lane];
#pragma unroll
    for (int off = 32; off > 0; off >>= 1) v += __shfl_down(v, off);
    if (lane == 0) {
      float l = v * invN + poolC[g] * invN * s2o + bout;
      logits[g] = l;
      out[1 + g] = 1.0f / (1.0f + expf(-l));         // y_pred
    }
  }
  __syncthreads();
  if (t < 64) {
    float term = 0.f;
    if (lane < B_GRAPHS) {
      float l = logits[lane];
      term = fmaxf(l, 0.f) - l * y[lane] + log1pf(expf(-fabsf(l)));
    }
#pragma unroll
    for (int off = 32; off > 0; off >>= 1) term += __shfl_down(term, off);
    if (lane == 0) out[0] = term / (float)B_GRAPHS;  // loss
  }
}

extern "C" void kernel_launch(void* const* d_in, const int* in_sizes, int n_in,
                              void* d_out, int out_size, void* d_ws, size_t ws_size,
                              hipStream_t stream) {
  const int*   node_ids = (const int*)d_in[0];
  const int*   src      = (const int*)d_in[1];
  const int*   dst      = (const int*)d_in[2];
  const float* ew       = (const float*)d_in[3];
  const float* y        = (const float*)d_in[4];
  const float* embeds   = (const float*)d_in[5];
  const float* W1       = (const float*)d_in[6];
  const float* b1       = (const float*)d_in[7];
  const float* W2       = (const float*)d_in[8];
  const float* b2       = (const float*)d_in[9];
  const float* W_out    = (const float*)d_in[10];
  const float* b_out    = (const float*)d_in[11];
  float* out = (float*)d_out;
  (void)in_sizes; (void)n_in; (void)out_size; (void)ws_size;

  char* ws = (char*)d_ws;
  size_t off = 0;
  auto alloc = [&](size_t bytes) {
    size_t r = off;
    off = (off + bytes + 511) & ~(size_t)511;
    return r;
  };
  size_t o_binCur = alloc(1024 * 4);                              // binCursor + sCursor
  size_t o_pool   = alloc((size_t)POOL_N * 4);
  size_t o_rowD   = alloc((size_t)(NT + 1) * 4);
  size_t o_cntD   = alloc((size_t)NT * 4);
  size_t o_P1p8   = alloc((size_t)V * 32 * 4);                    // 1.92 MB
  size_t o_h1p8   = alloc((size_t)(NT + 256) * 32 * 4);           // 12.8 MB + guard
  size_t o_stage  = alloc((size_t)NBIN * STAGE_STRIDE * 8);       // 14.4 MB
  size_t o_pay    = alloc(((size_t)NBIN * PAY_STRIDE + PAY_TAIL) * 8);  // 16.8 MB
  size_t o_stageS = alloc((size_t)NBIN * SS_STRIDE * 4);          // 7.2 MB

  int*      binCursor= (int*)(ws + o_binCur);
  int*      sCursor  = binCursor + 512;
  float*    pool     = (float*)(ws + o_pool);
  int*      rowD     = (int*)(ws + o_rowD);
  int*      cntD     = (int*)(ws + o_cntD);
  unsigned* P1p8     = (unsigned*)(ws + o_P1p8);
  unsigned* h1p8     = (unsigned*)(ws + o_h1p8);
  int2*     stage    = (int2*)(ws + o_stage);
  int2*     pay      = (int2*)(ws + o_pay);
  unsigned* stageS   = (unsigned*)(ws + o_stageS);
  int2*     payTail  = pay + (size_t)NBIN * PAY_STRIDE;
  // pool partials alias stage (dead after k_binsort; k_cpool runs after k_agg1)
  float*    part     = (float*)(ws + o_stage);                    // 10.0 MB < 14.4 MB

  (void)hipMemsetAsync(binCursor, 0, 1024 * 4, stream);
  k_pb<<<NFB + PROJ_BLOCKS, 512, 0, stream>>>(embeds, W1, b1, P1p8, pool, payTail,
                                              src, dst, ew, node_ids, binCursor, stage,
                                              h1p8);
  k_binsort<<<NBIN, 512, 0, stream>>>(stage, binCursor, rowD, cntD, pay, sCursor,
                                      stageS, pool + B_GRAPHS * D);
  k_agg1<<<NT / (4 * NPW1), 256, 0, stream>>>(pay, rowD, cntD, P1p8, h1p8);
  k_cpool<<<NBIN, 512, 0, stream>>>(stageS, sCursor, h1p8, part);
  k_reduce<<<B_GRAPHS * D / 64, 256, 0, stream>>>(part, pool);
  k_final<<<1, 256, 0, stream>>>(pool, pool + B_GRAPHS * D, W2, b2, W_out, b_out, y, out);
}